// Round 2
// baseline (32079.828 us; speedup 1.0000x reference)
//
#include <hip/hip_runtime.h>
#include <math.h>

// Problem constants (B,S,D fixed by reference setup_inputs)
#define B 64
#define S 2048
#define D 64
// TEMPERATURE = 8.0 -> multiply scores by 1/8
#define INV_TEMP 0.125f

// ---------------------------------------------------------------------------
// 16B direct global->LDS copy (DMA path: no VGPR round-trip, no ds_write
// bank conflicts). LDS dest must be wave-uniform base + lane*16; swizzled
// layouts are achieved by permuting the per-lane GLOBAL source address.
// ---------------------------------------------------------------------------
__device__ __forceinline__ void gload_lds16(const float* g, void* l) {
    __builtin_amdgcn_global_load_lds(
        (const __attribute__((address_space(1))) void*)g,
        (__attribute__((address_space(3))) void*)l, 16, 0, 0);
}

// LDS tiles are [64][64] floats. Swizzled tiles store logical element (r,c)
// at column (c ^ (((r>>2)&7)<<2)) so that b128 reads across 16 distinct rows
// hit distinct bank groups (XOR involution, float4 granularity).

// ---------------------------------------------------------------------------
// Kernel A: e = mask ? 0 : exp(q@k^T/8)  (UNNORMALIZED), rowsums -> out[row][0]
// Block = 64 q-rows, 256 threads, thread (tr=t>>4, tc=t&15) owns 4x4 tile.
// LDS: qs 16K + ks 16K = 32 KiB -> 4 blocks/CU with VGPR<=128.
// ---------------------------------------------------------------------------
__global__ __launch_bounds__(256, 4) void attn_scores_kernel(
    const float* __restrict__ qp, const float* __restrict__ kp,
    const int* __restrict__ maskp, float* __restrict__ attnp,
    float* __restrict__ outp /* rowsum scratch at out[b][row][0] */)
{
    __shared__ float qs[64][64];   // swizzled
    __shared__ float ks[64][64];   // swizzled

    // XCD-chunked swizzle: 2048 blocks % 8 == 0, contiguous 256 per XCD so
    // same-batch blocks share an XCD L2 for K.
    const int bid = blockIdx.x;
    const int swz = (bid & 7) * 256 + (bid >> 3);
    const int b   = swz >> 5;          // 64 batches
    const int r0  = (swz & 31) * 64;   // 32 row-tiles per batch

    const int t    = threadIdx.x;
    const int tr   = t >> 4;           // 0..15
    const int tc   = t & 15;           // 0..15
    const int rr   = tr * 4;
    const int cc   = tc * 4;
    const int qxor = (tr & 7) << 2;    // byte-col xor (in floats) for my q rows
    const int kxor = (tc & 7) << 2;    // for my k rows

    // ---- stage Q tile once (pre-swizzled global source) ----
    {
        const float* qsrc = qp + ((size_t)b * S + r0) * D;
#pragma unroll
        for (int i = 0; i < 4; ++i) {
            int f  = t + 256 * i;           // float4 slot 0..1023
            int r  = f >> 4;
            int c4 = f & 15;
            int sf = (r << 4) + (c4 ^ ((r >> 2) & 7));
            gload_lds16(qsrc + sf * 4, (char*)&qs[0][0] + (size_t)(f & ~63) * 16);
        }
    }

    const float* kbase = kp + (size_t)b * S * D;
    float rs[4] = {0.f, 0.f, 0.f, 0.f};

#pragma unroll 1
    for (int kt = 0; kt < 32; ++kt) {
        __syncthreads();   // previous tile's ks reads done
        // ---- stage K tile (pre-swizzled source) ----
        {
            const float* ksrc = kbase + (size_t)kt * 64 * D;
#pragma unroll
            for (int i = 0; i < 4; ++i) {
                int f  = t + 256 * i;
                int r  = f >> 4;
                int c4 = f & 15;
                int sf = (r << 4) + (c4 ^ ((r >> 2) & 7));
                gload_lds16(ksrc + sf * 4, (char*)&ks[0][0] + (size_t)(f & ~63) * 16);
            }
        }
        // mask tile for my 4x4 (independent of LDS; overlaps staging)
        int4 m4[4];
#pragma unroll
        for (int i = 0; i < 4; ++i)
            m4[i] = *(const int4*)(maskp + ((size_t)b * S + r0 + rr + i) * S
                                   + (size_t)kt * 64 + cc);
        __syncthreads();   // ks (and qs on kt=0) visible

        // ---- 4x4 score tile ----
        float sc[4][4];
#pragma unroll
        for (int i = 0; i < 4; ++i)
#pragma unroll
            for (int j = 0; j < 4; ++j) sc[i][j] = 0.f;

#pragma unroll
        for (int dstep = 0; dstep < 16; ++dstep) {
            const int dc = dstep * 4;
            float4 q4[4], k4[4];
#pragma unroll
            for (int i = 0; i < 4; ++i) q4[i] = *(const float4*)&qs[rr + i][dc ^ qxor];
#pragma unroll
            for (int j = 0; j < 4; ++j) k4[j] = *(const float4*)&ks[cc + j][dc ^ kxor];
#pragma unroll
            for (int i = 0; i < 4; ++i)
#pragma unroll
                for (int j = 0; j < 4; ++j)
                    sc[i][j] += q4[i].x * k4[j].x + q4[i].y * k4[j].y
                              + q4[i].z * k4[j].z + q4[i].w * k4[j].w;
        }

        // ---- mask + exp, write unnormalized e, accumulate rowsum ----
        const size_t abase = ((size_t)b * S + r0 + rr) * S + (size_t)kt * 64 + cc;
#pragma unroll
        for (int i = 0; i < 4; ++i) {
            float4 e4;
            e4.x = m4[i].x ? 0.f : __expf(sc[i][0] * INV_TEMP);
            e4.y = m4[i].y ? 0.f : __expf(sc[i][1] * INV_TEMP);
            e4.z = m4[i].z ? 0.f : __expf(sc[i][2] * INV_TEMP);
            e4.w = m4[i].w ? 0.f : __expf(sc[i][3] * INV_TEMP);
            rs[i] += (e4.x + e4.y) + (e4.z + e4.w);
            *(float4*)(attnp + abase + (size_t)i * S) = e4;
        }
    }

    // ---- rowsum reduce over the 16 tc lanes; stash at out[b][row][0] ----
    float* outb = outp + ((size_t)b * S + r0) * D;
#pragma unroll
    for (int i = 0; i < 4; ++i) {
        float s = rs[i];
        s += __shfl_xor(s, 1, 16);
        s += __shfl_xor(s, 2, 16);
        s += __shfl_xor(s, 4, 16);
        s += __shfl_xor(s, 8, 16);
        if (tc == 0) outb[(size_t)(rr + i) * D] = s;
    }
}

// ---------------------------------------------------------------------------
// Kernel B: normalize attn in place + out = attn @ v, fused.
// Reads e tile once from HBM (gload_lds for PV; register re-read = L2 hit for
// the normalize write-back). Rowsums come from out[b][row][0] (read before
// the epilogue overwrites out). LDS: es 16K + vs 16K = 32 KiB.
// ---------------------------------------------------------------------------
__global__ __launch_bounds__(256, 4) void attn_pv_kernel(
    const float* __restrict__ vp, float* __restrict__ attnp,
    float* __restrict__ outp)
{
    __shared__ float es[64][64];   // swizzled
    __shared__ float vs[64][64];   // linear (reads are row-uniform)

    const int bid = blockIdx.x;
    const int swz = (bid & 7) * 256 + (bid >> 3);
    const int b   = swz >> 5;
    const int r0  = (swz & 31) * 64;

    const int t    = threadIdx.x;
    const int tr   = t >> 4;
    const int tc   = t & 15;
    const int rr   = tr * 4;
    const int cc   = tc * 4;
    const int qxor = (tr & 7) << 2;

    // rowsum -> inverse (broadcast loads; completed before first barrier,
    // epilogue write of out comes only after many barriers)
    float inv4[4];
#pragma unroll
    for (int i = 0; i < 4; ++i)
        inv4[i] = 1.f / outp[((size_t)b * S + r0 + rr + i) * D];

    const float* vbase = vp + (size_t)b * S * D;
    float4 acc[4];
#pragma unroll
    for (int i = 0; i < 4; ++i) acc[i] = make_float4(0.f, 0.f, 0.f, 0.f);

#pragma unroll 1
    for (int kt = 0; kt < 32; ++kt) {
        __syncthreads();   // previous tile's LDS reads done
        const float* esrc = attnp + ((size_t)b * S + r0) * S + (size_t)kt * 64;
        // ---- stage e tile (pre-swizzled source, row stride S) ----
#pragma unroll
        for (int i = 0; i < 4; ++i) {
            int f  = t + 256 * i;
            int r  = f >> 4;
            int c4 = f & 15;
            int xr = (r >> 2) & 7;
            gload_lds16(esrc + (size_t)r * S + ((c4 ^ xr) << 2),
                        (char*)&es[0][0] + (size_t)(f & ~63) * 16);
        }
        // ---- stage V tile (linear) ----
        {
            const float* vsrc = vbase + (size_t)kt * 64 * D;
#pragma unroll
            for (int i = 0; i < 4; ++i) {
                int f = t + 256 * i;
                gload_lds16(vsrc + f * 4, (char*)&vs[0][0] + (size_t)(f & ~63) * 16);
            }
        }
        // my 4x4 e sub-tile for the normalize write-back (L2 hit: tile just
        // fetched). Read BEFORE the barrier; store after it.
        float4 wb[4];
#pragma unroll
        for (int i = 0; i < 4; ++i)
            wb[i] = *(const float4*)(esrc + (size_t)(rr + i) * S + cc);
        __syncthreads();   // es/vs visible; all wb reads drained

        // ---- normalized attn write-back ----
#pragma unroll
        for (int i = 0; i < 4; ++i) {
            float4 w;
            w.x = wb[i].x * inv4[i];
            w.y = wb[i].y * inv4[i];
            w.z = wb[i].z * inv4[i];
            w.w = wb[i].w * inv4[i];
            *(float4*)(attnp + ((size_t)b * S + r0 + rr + i) * S
                       + (size_t)kt * 64 + cc) = w;
        }

        // ---- PV: acc[4][4] += e-tile @ v-tile ----
#pragma unroll
        for (int kk = 0; kk < 64; kk += 4) {
            float4 e4[4], v4[4];
#pragma unroll
            for (int i = 0; i < 4; ++i) e4[i] = *(const float4*)&es[rr + i][kk ^ qxor];
#pragma unroll
            for (int u = 0; u < 4; ++u) v4[u] = *(const float4*)&vs[kk + u][cc];
#pragma unroll
            for (int i = 0; i < 4; ++i) {
                acc[i].x += e4[i].x * v4[0].x + e4[i].y * v4[1].x
                          + e4[i].z * v4[2].x + e4[i].w * v4[3].x;
                acc[i].y += e4[i].x * v4[0].y + e4[i].y * v4[1].y
                          + e4[i].z * v4[2].y + e4[i].w * v4[3].y;
                acc[i].z += e4[i].x * v4[0].z + e4[i].y * v4[1].z
                          + e4[i].z * v4[2].z + e4[i].w * v4[3].z;
                acc[i].w += e4[i].x * v4[0].w + e4[i].y * v4[1].w
                          + e4[i].z * v4[2].w + e4[i].w * v4[3].w;
            }
        }
    }

    // ---- epilogue: out = acc * inv (overwrites the rowsum scratch) ----
#pragma unroll
    for (int i = 0; i < 4; ++i) {
        float4 o;
        o.x = acc[i].x * inv4[i];
        o.y = acc[i].y * inv4[i];
        o.z = acc[i].z * inv4[i];
        o.w = acc[i].w * inv4[i];
        *(float4*)(outp + ((size_t)b * S + r0 + rr + i) * D + cc) = o;
    }
}

// ---------------------------------------------------------------------------
extern "C" void kernel_launch(void* const* d_in, const int* in_sizes, int n_in,
                              void* d_out, int out_size, void* d_ws, size_t ws_size,
                              hipStream_t stream) {
    const float* q = (const float*)d_in[0];
    const float* k = (const float*)d_in[1];
    const float* v = (const float*)d_in[2];
    const int* mask = (const int*)d_in[3];   // bool -> int32 in harness

    float* out  = (float*)d_out;                       // (B,S,D) first
    float* attn = out + (size_t)B * S * D;             // then (B,S,S)

    attn_scores_kernel<<<dim3((S / 64) * B), 256, 0, stream>>>(q, k, mask, attn, out);
    attn_pv_kernel<<<dim3((S / 64) * B), 256, 0, stream>>>(v, attn, out);
}